// Round 3
// baseline (235.174 us; speedup 1.0000x reference)
//
#include <hip/hip_runtime.h>

// Problem dims (fixed): B=4, T=2048, C=64, H=6, D=64, scale = 1/8.
// I/O dtype: float32 (bf16-rounded values — the test's "bf16" refers to data
// precision, not storage; round-2 NaN proved storage is f32). Internal
// Q/K/V/att buffers are bf16 (lossless given bf16-rounded inputs).

typedef unsigned short u16t;
typedef __attribute__((ext_vector_type(8))) short short8;   // 8 bf16 = 4 VGPRs (MFMA A/B frag)
typedef __attribute__((ext_vector_type(4))) float float4v;  // MFMA C/D frag

#define MFMA16(a, b, c) __builtin_amdgcn_mfma_f32_16x16x32_bf16((a), (b), (c), 0, 0, 0)

__device__ __forceinline__ float bf2f(u16t u) {
  return __uint_as_float(((unsigned)u) << 16);
}
__device__ __forceinline__ u16t f2bf(float f) {
  unsigned u = __float_as_uint(f);
  u += 0x7fffu + ((u >> 16) & 1u);  // round-nearest-even
  return (u16t)(u >> 16);
}

constexpr int Bb = 4, Tt = 2048, Cc = 64, Hh = 6, Dd = 64;
constexpr int BH = Bb * Hh;         // 24
constexpr int NQT = Tt / 64;        // 32 q-tiles of 64 rows
constexpr int LDT = 72;             // padded LDS row stride (144 B: 16B-aligned, conflict-free b128)

// ---------------------------------------------------------------------------
// Kernel 1: QKV projection. q[bh,t,d] = sum_c x[b,t,c] Wq[h,c,d]  (q pre-scaled
// by 1/8), k from y/Wk, v from y/Wv stored TRANSPOSED as Vt[bh,d,t].
// Block: 256 thr = 4 t-rows x 64 d. Grid: BH * T/4 = 12288.
// ---------------------------------------------------------------------------
__global__ __launch_bounds__(256) void qkv_kernel(
    const float* __restrict__ x, const float* __restrict__ y,
    const float* __restrict__ Wq, const float* __restrict__ Wk,
    const float* __restrict__ Wv,
    u16t* __restrict__ Q, u16t* __restrict__ K, u16t* __restrict__ Vt) {
  const int nt4 = Tt / 4;  // 512
  int bid = blockIdx.x;
  int bh = bid / nt4, t4 = bid - bh * nt4;
  int b = bh / Hh, h = bh - b * Hh;
  int tid = threadIdx.x;
  int r = tid >> 6, d = tid & 63;

  __shared__ float xs[4 * 64], ys[4 * 64];
  __shared__ u16t vsm[64 * 4];

  // 4 rows of x and y: 256 contiguous floats each, one elem per thread.
  size_t rowbase = ((size_t)b * Tt + t4 * 4) * Cc;
  xs[tid] = x[rowbase + tid];
  ys[tid] = y[rowbase + tid];
  __syncthreads();

  const float* wq = Wq + h * Cc * Dd;
  const float* wk = Wk + h * Cc * Dd;
  const float* wv = Wv + h * Cc * Dd;

  float qa = 0.f, ka = 0.f, va = 0.f;
#pragma unroll 8
  for (int c = 0; c < 64; ++c) {
    float xv = xs[r * 64 + c];  // broadcast within wave (wave == fixed r)
    float yv = ys[r * 64 + c];
    qa += xv * wq[c * 64 + d];  // lanes d: coalesced 256B line
    ka += yv * wk[c * 64 + d];
    va += yv * wv[c * 64 + d];
  }
  int t = t4 * 4 + r;
  size_t qi = ((size_t)bh * Tt + t) * Dd + d;
  Q[qi] = f2bf(qa * 0.125f);  // pre-scale by D^-0.5
  K[qi] = f2bf(ka);
  vsm[d * 4 + r] = f2bf(va);
  __syncthreads();
  if (tid < 64) {  // write Vt[bh, d=tid, t4*4 .. +3] as one 8B chunk
    uint2 val = *(const uint2*)&vsm[tid * 4];
    *(uint2*)&Vt[((size_t)bh * 64 + tid) * Tt + t4 * 4] = val;
  }
}

// ---------------------------------------------------------------------------
// Kernel 2: causal flash attention, bf16 MFMA 16x16x32.
// Block: 256 thr = 4 waves; block owns 64 q-rows (one q-tile) of one (b,h);
// wave w owns rows w*16..w*16+15. K-tile/Vt-tile (64x64) staged in LDS.
// Online softmax: each q-row lives in one 16-lane group (C-layout row =
// quad*4+reg), so row max/sum are 4-step shuffle-xor reductions.
// P goes C-layout -> LDS -> A-layout (documented round trip).
// Grid: BH * 32 = 768 (qt descending for tail-latency).
// ---------------------------------------------------------------------------
__global__ __launch_bounds__(256) void attn_kernel(
    const u16t* __restrict__ Q, const u16t* __restrict__ K,
    const u16t* __restrict__ Vt, u16t* __restrict__ att) {
  __shared__ __align__(16) u16t Kl[64 * LDT];
  __shared__ __align__(16) u16t Vl[64 * LDT];
  __shared__ __align__(16) u16t Pl[4 * 16 * LDT];

  int bid = blockIdx.x;
  int bh = bid % BH;
  int qt = (NQT - 1) - bid / BH;  // big tiles first
  int b = bh / Hh, h = bh - (bh / Hh) * Hh;
  int tid = threadIdx.x;
  int w = tid >> 6;
  int lane = tid & 63;
  int l15 = lane & 15, q4 = lane >> 4;

  // Q A-fragments (2 k-chunks of 32), straight from global (rows = wave rows).
  const u16t* Qbase = Q + ((size_t)bh * Tt + qt * 64 + w * 16 + l15) * Dd;
  short8 qf0 = *(const short8*)(Qbase + q4 * 8);
  short8 qf1 = *(const short8*)(Qbase + 32 + q4 * 8);

  float4v O[4];
#pragma unroll
  for (int nc = 0; nc < 4; ++nc) O[nc] = (float4v){0.f, 0.f, 0.f, 0.f};
  float m_[4], l_[4];
#pragma unroll
  for (int i = 0; i < 4; ++i) { m_[i] = -1e30f; l_[i] = 0.f; }

  const u16t* Kbh = K + (size_t)bh * Tt * Dd;
  const u16t* Vbh = Vt + (size_t)bh * Dd * Tt;
  u16t* Pw = Pl + w * 16 * LDT;

  for (int jt = 0; jt <= qt; ++jt) {
    __syncthreads();  // previous iteration's LDS reads done
    // Stage K tile [j 0..63][c 0..63] and Vt tile [d 0..63][j 0..63].
    {
      const u16t* ksrc = Kbh + (size_t)jt * 64 * 64;  // contiguous 8KB
#pragma unroll
      for (int i = 0; i < 2; ++i) {
        int idx = tid * 2 + i;  // 0..511 chunks of 8 bf16
        int row = idx >> 3, c8 = idx & 7;
        *(uint4*)&Kl[row * LDT + c8 * 8] = *(const uint4*)(ksrc + row * 64 + c8 * 8);
        *(uint4*)&Vl[row * LDT + c8 * 8] =
            *(const uint4*)(Vbh + (size_t)row * Tt + jt * 64 + c8 * 8);
      }
    }
    __syncthreads();

    // S = Q * K^T  (per wave: 16 rows x 64 cols, 8 MFMAs)
    float4v S[4];
#pragma unroll
    for (int nc = 0; nc < 4; ++nc) {
      short8 kf0 = *(const short8*)&Kl[(nc * 16 + l15) * LDT + q4 * 8];
      short8 kf1 = *(const short8*)&Kl[(nc * 16 + l15) * LDT + 32 + q4 * 8];
      float4v s = (float4v){0.f, 0.f, 0.f, 0.f};
      s = MFMA16(qf0, kf0, s);
      s = MFMA16(qf1, kf1, s);
      S[nc] = s;
    }

    // Causal mask on the diagonal tile (jt == qt): col > row -> -inf.
    if (jt == qt) {
      int rloc = w * 16 + q4 * 4;
#pragma unroll
      for (int nc = 0; nc < 4; ++nc)
#pragma unroll
        for (int reg = 0; reg < 4; ++reg)
          if (nc * 16 + l15 > rloc + reg) S[nc][reg] = -1e30f;
    }

    // Online softmax update. Row r = q4*4+reg spans the 16 lanes of group q4.
    float alpha[4];
#pragma unroll
    for (int reg = 0; reg < 4; ++reg) {
      float v = fmaxf(fmaxf(S[0][reg], S[1][reg]), fmaxf(S[2][reg], S[3][reg]));
#pragma unroll
      for (int off = 1; off < 16; off <<= 1) v = fmaxf(v, __shfl_xor(v, off));
      float mn = fmaxf(m_[reg], v);
      alpha[reg] = __expf(m_[reg] - mn);
      m_[reg] = mn;
    }
#pragma unroll
    for (int reg = 0; reg < 4; ++reg) {
      float s = 0.f;
#pragma unroll
      for (int nc = 0; nc < 4; ++nc) {
        float p = __expf(S[nc][reg] - m_[reg]);
        S[nc][reg] = p;
        s += p;
      }
#pragma unroll
      for (int off = 1; off < 16; off <<= 1) s += __shfl_xor(s, off);
      l_[reg] = l_[reg] * alpha[reg] + s;
    }

    // P (C-layout) -> LDS, rescale O, then PV with P in A-layout.
#pragma unroll
    for (int nc = 0; nc < 4; ++nc)
#pragma unroll
      for (int reg = 0; reg < 4; ++reg)
        Pw[(q4 * 4 + reg) * LDT + nc * 16 + l15] = f2bf(S[nc][reg]);
#pragma unroll
    for (int nc = 0; nc < 4; ++nc)
#pragma unroll
      for (int reg = 0; reg < 4; ++reg) O[nc][reg] *= alpha[reg];
    __syncthreads();  // orders P write -> P read (all waves hit it)

    short8 pf0 = *(const short8*)&Pw[l15 * LDT + q4 * 8];
    short8 pf1 = *(const short8*)&Pw[l15 * LDT + 32 + q4 * 8];
#pragma unroll
    for (int nc = 0; nc < 4; ++nc) {
      short8 vf0 = *(const short8*)&Vl[(nc * 16 + l15) * LDT + q4 * 8];
      short8 vf1 = *(const short8*)&Vl[(nc * 16 + l15) * LDT + 32 + q4 * 8];
      O[nc] = MFMA16(pf0, vf0, O[nc]);
      O[nc] = MFMA16(pf1, vf1, O[nc]);
    }
  }

  // Epilogue: normalize and write att[b, t, h*64 + d] (internal bf16).
#pragma unroll
  for (int reg = 0; reg < 4; ++reg) {
    float inv = 1.0f / l_[reg];
    int t = qt * 64 + w * 16 + q4 * 4 + reg;
    size_t obase = ((size_t)b * Tt + t) * (Hh * Dd) + h * Dd;
#pragma unroll
    for (int nc = 0; nc < 4; ++nc)
      att[obase + nc * 16 + l15] = f2bf(O[nc][reg] * inv);
  }
}

// ---------------------------------------------------------------------------
// Kernel 3: out = att[B*T, 384] @ W_proj[384, 64] + b_proj  (f32 out).
// Block: 256 thr = 4 rows x 64 cols. Grid: B*T/4 = 2048.
// ---------------------------------------------------------------------------
__global__ __launch_bounds__(256) void proj_kernel(
    const u16t* __restrict__ att, const float* __restrict__ Wp,
    const float* __restrict__ bp, float* __restrict__ out) {
  int bid = blockIdx.x;
  int tid = threadIdx.x;
  int r = tid >> 6, cc = tid & 63;
  __shared__ float as[4 * 384];
  size_t rowbase = (size_t)bid * 4 * 384;
#pragma unroll
  for (int i = 0; i < 6; ++i) as[tid + i * 256] = bf2f(att[rowbase + tid + i * 256]);
  __syncthreads();
  float acc = bp[cc];
#pragma unroll 8
  for (int i = 0; i < 384; ++i) acc += as[r * 384 + i] * Wp[i * 64 + cc];
  out[(size_t)bid * 256 + r * 64 + cc] = acc;
}

// ---------------------------------------------------------------------------
extern "C" void kernel_launch(void* const* d_in, const int* in_sizes, int n_in,
                              void* d_out, int out_size, void* d_ws, size_t ws_size,
                              hipStream_t stream) {
  const float* x  = (const float*)d_in[0];
  const float* y  = (const float*)d_in[1];
  const float* Wq = (const float*)d_in[2];
  const float* Wk = (const float*)d_in[3];
  const float* Wv = (const float*)d_in[4];
  const float* Wp = (const float*)d_in[5];
  const float* bp = (const float*)d_in[6];
  float* out = (float*)d_out;

  const size_t NBH = (size_t)BH * Tt * Dd;  // 3,145,728 elems
  u16t* Qs  = (u16t*)d_ws;
  u16t* Ks  = Qs + NBH;
  u16t* Vts = Ks + NBH;
  u16t* attb = Vts + NBH;  // [B, T, H*D] internal bf16

  qkv_kernel<<<BH * (Tt / 4), 256, 0, stream>>>(x, y, Wq, Wk, Wv, Qs, Ks, Vts);
  attn_kernel<<<BH * NQT, 256, 0, stream>>>(Qs, Ks, Vts, attb);
  proj_kernel<<<(Bb * Tt) / 4, 256, 0, stream>>>(attb, Wp, bp, out);
}

// Round 4
// 151.919 us; speedup vs baseline: 1.5480x; 1.5480x over previous
//
#include <hip/hip_runtime.h>

// Problem dims (fixed): B=4, T=2048, C=64, H=6, D=64, scale = 1/8.
// I/O dtype: float32 (bf16-rounded values). Internal Q/K/Vt/att are bf16.
// Round-4: qkv + proj rebuilt on MFMA (the 82/65 us latency-bound VALU loops
// were the top cost); attn loses its redundant per-wave P barrier.

typedef unsigned short u16t;
typedef __attribute__((ext_vector_type(8))) short short8;   // 8 bf16 = 4 VGPRs (MFMA A/B frag)
typedef __attribute__((ext_vector_type(4))) float float4v;  // MFMA C/D frag

#define MFMA16(a, b, c) __builtin_amdgcn_mfma_f32_16x16x32_bf16((a), (b), (c), 0, 0, 0)

__device__ __forceinline__ float bf2f(u16t u) {
  return __uint_as_float(((unsigned)u) << 16);
}
__device__ __forceinline__ u16t f2bf(float f) {
  unsigned u = __float_as_uint(f);
  u += 0x7fffu + ((u >> 16) & 1u);  // round-nearest-even
  return (u16t)(u >> 16);
}
// Load 8 consecutive f32 and pack to bf16 A-fragment.
__device__ __forceinline__ short8 load8_f32_bf16(const float* p) {
  float4 f0 = *(const float4*)p;
  float4 f1 = *(const float4*)(p + 4);
  short8 r;
  r[0] = (short)f2bf(f0.x); r[1] = (short)f2bf(f0.y);
  r[2] = (short)f2bf(f0.z); r[3] = (short)f2bf(f0.w);
  r[4] = (short)f2bf(f1.x); r[5] = (short)f2bf(f1.y);
  r[6] = (short)f2bf(f1.z); r[7] = (short)f2bf(f1.w);
  return r;
}

constexpr int Bb = 4, Tt = 2048, Cc = 64, Hh = 6, Dd = 64;
constexpr int BH = Bb * Hh;         // 24
constexpr int NQT = Tt / 64;        // 32 q-tiles of 64 rows
constexpr int LDT = 72;             // padded LDS row stride (144 B: 16B-aligned b128)

// ---------------------------------------------------------------------------
// Kernel 1: QKV projection via MFMA. Per block: one (b,h), 64 t-rows.
// Wq/Wk/Wv staged TRANSPOSED in LDS as bf16 (B-operand layout B[n=d][k=c] —
// same pattern as attn's K usage, HW-verified). x/y A-frags loaded directly
// from global f32. V bounced through LDS to write Vt[bh,d,t] coalesced.
// Grid: BH * 32 = 768, 256 thr (4 waves x 16 rows).
// ---------------------------------------------------------------------------
__global__ __launch_bounds__(256) void qkv_kernel(
    const float* __restrict__ x, const float* __restrict__ y,
    const float* __restrict__ Wq, const float* __restrict__ Wk,
    const float* __restrict__ Wv,
    u16t* __restrict__ Q, u16t* __restrict__ K, u16t* __restrict__ Vt) {
  __shared__ __align__(16) u16t wtq[64 * LDT];
  __shared__ __align__(16) u16t wtk[64 * LDT];
  __shared__ __align__(16) u16t wtv[64 * LDT];
  __shared__ __align__(16) u16t vl[64 * LDT];

  int bid = blockIdx.x;
  int bh = bid >> 5, tt = bid & 31;
  int b = bh / Hh, h = bh - b * Hh;
  int tid = threadIdx.x;
  int w = tid >> 6, lane = tid & 63;
  int l15 = lane & 15, q4 = lane >> 4;

  // Stage weights transposed: wt[d][c] = W[c][d], bf16. (8-way bank scatter,
  // once per block — accepted.)
  {
    const float* wq = Wq + h * 4096;
    const float* wk = Wk + h * 4096;
    const float* wv = Wv + h * 4096;
#pragma unroll
    for (int i = 0; i < 16; ++i) {
      int idx = tid + i * 256;  // 0..4095, coalesced reads
      int c = idx >> 6, d = idx & 63;
      wtq[d * LDT + c] = f2bf(wq[idx]);
      wtk[d * LDT + c] = f2bf(wk[idx]);
      wtv[d * LDT + c] = f2bf(wv[idx]);
    }
  }

  // A-fragments for this wave's 16 rows (rows = tt*64 + w*16 + l15).
  int trow = tt * 64 + w * 16 + l15;
  const float* xrow = x + ((size_t)b * Tt + trow) * Cc;
  const float* yrow = y + ((size_t)b * Tt + trow) * Cc;
  short8 xa[2], ya[2];
#pragma unroll
  for (int kc = 0; kc < 2; ++kc) {
    xa[kc] = load8_f32_bf16(xrow + kc * 32 + q4 * 8);
    ya[kc] = load8_f32_bf16(yrow + kc * 32 + q4 * 8);
  }
  __syncthreads();

  float4v qa4[4], ka4[4], va4[4];
#pragma unroll
  for (int nc = 0; nc < 4; ++nc) {
    qa4[nc] = (float4v){0.f, 0.f, 0.f, 0.f};
    ka4[nc] = (float4v){0.f, 0.f, 0.f, 0.f};
    va4[nc] = (float4v){0.f, 0.f, 0.f, 0.f};
  }
#pragma unroll
  for (int nc = 0; nc < 4; ++nc) {
#pragma unroll
    for (int kc = 0; kc < 2; ++kc) {
      int off = (nc * 16 + l15) * LDT + kc * 32 + q4 * 8;
      short8 bq = *(const short8*)&wtq[off];
      short8 bk = *(const short8*)&wtk[off];
      short8 bv = *(const short8*)&wtv[off];
      qa4[nc] = MFMA16(xa[kc], bq, qa4[nc]);
      ka4[nc] = MFMA16(ya[kc], bk, ka4[nc]);
      va4[nc] = MFMA16(ya[kc], bv, va4[nc]);
    }
  }

  // Q (pre-scaled by 1/8) and K: direct bf16 stores (C-layout: row=q4*4+reg,
  // col=nc*16+l15). V: bounce through LDS for coalesced transposed write.
#pragma unroll
  for (int reg = 0; reg < 4; ++reg) {
    int t = tt * 64 + w * 16 + q4 * 4 + reg;
    size_t base = ((size_t)bh * Tt + t) * Dd;
#pragma unroll
    for (int nc = 0; nc < 4; ++nc) {
      Q[base + nc * 16 + l15] = f2bf(qa4[nc][reg] * 0.125f);
      K[base + nc * 16 + l15] = f2bf(ka4[nc][reg]);
      vl[(nc * 16 + l15) * LDT + w * 16 + q4 * 4 + reg] = f2bf(va4[nc][reg]);
    }
  }
  __syncthreads();
  // Cooperative coalesced write of Vt tile [d 0..63][t tt*64..+63].
#pragma unroll
  for (int i = 0; i < 2; ++i) {
    int id = tid * 2 + i;  // 0..511 chunks of 8 bf16
    int d = id >> 3, c8 = id & 7;
    *(uint4*)&Vt[((size_t)bh * 64 + d) * Tt + tt * 64 + c8 * 8] =
        *(const uint4*)&vl[d * LDT + c8 * 8];
  }
}

// ---------------------------------------------------------------------------
// Kernel 2: causal flash attention, bf16 MFMA 16x16x32 (unchanged except the
// per-wave P barrier is removed — Pl is wave-private; compiler lgkmcnt orders
// the same-object ds_write -> ds_read).
// ---------------------------------------------------------------------------
__global__ __launch_bounds__(256) void attn_kernel(
    const u16t* __restrict__ Q, const u16t* __restrict__ K,
    const u16t* __restrict__ Vt, u16t* __restrict__ att) {
  __shared__ __align__(16) u16t Kl[64 * LDT];
  __shared__ __align__(16) u16t Vl[64 * LDT];
  __shared__ __align__(16) u16t Pl[4 * 16 * LDT];

  int bid = blockIdx.x;
  int bh = bid % BH;
  int qt = (NQT - 1) - bid / BH;  // big tiles first
  int b = bh / Hh, h = bh - (bh / Hh) * Hh;
  int tid = threadIdx.x;
  int w = tid >> 6;
  int lane = tid & 63;
  int l15 = lane & 15, q4 = lane >> 4;

  const u16t* Qbase = Q + ((size_t)bh * Tt + qt * 64 + w * 16 + l15) * Dd;
  short8 qf0 = *(const short8*)(Qbase + q4 * 8);
  short8 qf1 = *(const short8*)(Qbase + 32 + q4 * 8);

  float4v O[4];
#pragma unroll
  for (int nc = 0; nc < 4; ++nc) O[nc] = (float4v){0.f, 0.f, 0.f, 0.f};
  float m_[4], l_[4];
#pragma unroll
  for (int i = 0; i < 4; ++i) { m_[i] = -1e30f; l_[i] = 0.f; }

  const u16t* Kbh = K + (size_t)bh * Tt * Dd;
  const u16t* Vbh = Vt + (size_t)bh * Dd * Tt;
  u16t* Pw = Pl + w * 16 * LDT;

  for (int jt = 0; jt <= qt; ++jt) {
    __syncthreads();  // previous iteration's LDS reads done
    {
      const u16t* ksrc = Kbh + (size_t)jt * 64 * 64;  // contiguous 8KB
#pragma unroll
      for (int i = 0; i < 2; ++i) {
        int idx = tid * 2 + i;
        int row = idx >> 3, c8 = idx & 7;
        *(uint4*)&Kl[row * LDT + c8 * 8] = *(const uint4*)(ksrc + row * 64 + c8 * 8);
        *(uint4*)&Vl[row * LDT + c8 * 8] =
            *(const uint4*)(Vbh + (size_t)row * Tt + jt * 64 + c8 * 8);
      }
    }
    __syncthreads();

    float4v S[4];
#pragma unroll
    for (int nc = 0; nc < 4; ++nc) {
      short8 kf0 = *(const short8*)&Kl[(nc * 16 + l15) * LDT + q4 * 8];
      short8 kf1 = *(const short8*)&Kl[(nc * 16 + l15) * LDT + 32 + q4 * 8];
      float4v s = (float4v){0.f, 0.f, 0.f, 0.f};
      s = MFMA16(qf0, kf0, s);
      s = MFMA16(qf1, kf1, s);
      S[nc] = s;
    }

    if (jt == qt) {
      int rloc = w * 16 + q4 * 4;
#pragma unroll
      for (int nc = 0; nc < 4; ++nc)
#pragma unroll
        for (int reg = 0; reg < 4; ++reg)
          if (nc * 16 + l15 > rloc + reg) S[nc][reg] = -1e30f;
    }

    float alpha[4];
#pragma unroll
    for (int reg = 0; reg < 4; ++reg) {
      float v = fmaxf(fmaxf(S[0][reg], S[1][reg]), fmaxf(S[2][reg], S[3][reg]));
#pragma unroll
      for (int off = 1; off < 16; off <<= 1) v = fmaxf(v, __shfl_xor(v, off));
      float mn = fmaxf(m_[reg], v);
      alpha[reg] = __expf(m_[reg] - mn);
      m_[reg] = mn;
    }
#pragma unroll
    for (int reg = 0; reg < 4; ++reg) {
      float s = 0.f;
#pragma unroll
      for (int nc = 0; nc < 4; ++nc) {
        float p = __expf(S[nc][reg] - m_[reg]);
        S[nc][reg] = p;
        s += p;
      }
#pragma unroll
      for (int off = 1; off < 16; off <<= 1) s += __shfl_xor(s, off);
      l_[reg] = l_[reg] * alpha[reg] + s;
    }

#pragma unroll
    for (int nc = 0; nc < 4; ++nc)
#pragma unroll
      for (int reg = 0; reg < 4; ++reg)
        Pw[(q4 * 4 + reg) * LDT + nc * 16 + l15] = f2bf(S[nc][reg]);
#pragma unroll
    for (int nc = 0; nc < 4; ++nc)
#pragma unroll
      for (int reg = 0; reg < 4; ++reg) O[nc][reg] *= alpha[reg];
    // (no barrier: Pw is wave-private)

    short8 pf0 = *(const short8*)&Pw[l15 * LDT + q4 * 8];
    short8 pf1 = *(const short8*)&Pw[l15 * LDT + 32 + q4 * 8];
#pragma unroll
    for (int nc = 0; nc < 4; ++nc) {
      short8 vf0 = *(const short8*)&Vl[(nc * 16 + l15) * LDT + q4 * 8];
      short8 vf1 = *(const short8*)&Vl[(nc * 16 + l15) * LDT + 32 + q4 * 8];
      O[nc] = MFMA16(pf0, vf0, O[nc]);
      O[nc] = MFMA16(pf1, vf1, O[nc]);
    }
  }

#pragma unroll
  for (int reg = 0; reg < 4; ++reg) {
    float inv = 1.0f / l_[reg];
    int t = qt * 64 + w * 16 + q4 * 4 + reg;
    size_t obase = ((size_t)b * Tt + t) * (Hh * Dd) + h * Dd;
#pragma unroll
    for (int nc = 0; nc < 4; ++nc)
      att[obase + nc * 16 + l15] = f2bf(O[nc][reg] * inv);
  }
}

// ---------------------------------------------------------------------------
// Kernel 3: out = att[8192, 384] @ W_proj[384, 64] + b_proj, via MFMA.
// Wp staged transposed in LDS (Wpt[c][i], bf16, stride 392). A-frags from
// bf16 att directly. Grid: 8192/64 = 128 blocks, 4 waves x 16 rows.
// ---------------------------------------------------------------------------
constexpr int LDP = 392;  // 384+8; row stride 784 B (16B-aligned)

__global__ __launch_bounds__(256) void proj_kernel(
    const u16t* __restrict__ att, const float* __restrict__ Wp,
    const float* __restrict__ bp, float* __restrict__ out) {
  __shared__ __align__(16) u16t wpt[64 * LDP];  // 50176 B

  int bid = blockIdx.x;
  int tid = threadIdx.x;
  int w = tid >> 6, lane = tid & 63;
  int l15 = lane & 15, q4 = lane >> 4;

  // Stage Wp transposed: wpt[c][i] = Wp[i][c], bf16.
#pragma unroll 8
  for (int i = 0; i < 96; ++i) {
    int idx = tid + i * 256;  // 0..24575, coalesced reads
    int r = idx >> 6, c = idx & 63;
    wpt[c * LDP + r] = f2bf(Wp[idx]);
  }
  __syncthreads();

  int row0 = bid * 64 + w * 16;  // this wave's 16 rows
  const u16t* arow = att + (size_t)(row0 + l15) * 384;

  float4v acc[4];
#pragma unroll
  for (int nc = 0; nc < 4; ++nc) acc[nc] = (float4v){0.f, 0.f, 0.f, 0.f};

#pragma unroll
  for (int kc = 0; kc < 12; ++kc) {
    short8 a = *(const short8*)(arow + kc * 32 + q4 * 8);
#pragma unroll
    for (int nc = 0; nc < 4; ++nc) {
      short8 bfr = *(const short8*)&wpt[(nc * 16 + l15) * LDP + kc * 32 + q4 * 8];
      acc[nc] = MFMA16(a, bfr, acc[nc]);
    }
  }

  float bv[4];
#pragma unroll
  for (int nc = 0; nc < 4; ++nc) bv[nc] = bp[nc * 16 + l15];
#pragma unroll
  for (int reg = 0; reg < 4; ++reg) {
    int t = row0 + q4 * 4 + reg;
    size_t obase = (size_t)t * 64;
#pragma unroll
    for (int nc = 0; nc < 4; ++nc)
      out[obase + nc * 16 + l15] = acc[nc][reg] + bv[nc];
  }
}

// ---------------------------------------------------------------------------
extern "C" void kernel_launch(void* const* d_in, const int* in_sizes, int n_in,
                              void* d_out, int out_size, void* d_ws, size_t ws_size,
                              hipStream_t stream) {
  const float* x  = (const float*)d_in[0];
  const float* y  = (const float*)d_in[1];
  const float* Wq = (const float*)d_in[2];
  const float* Wk = (const float*)d_in[3];
  const float* Wv = (const float*)d_in[4];
  const float* Wp = (const float*)d_in[5];
  const float* bp = (const float*)d_in[6];
  float* out = (float*)d_out;

  const size_t NBH = (size_t)BH * Tt * Dd;  // 3,145,728 elems
  u16t* Qs  = (u16t*)d_ws;
  u16t* Ks  = Qs + NBH;
  u16t* Vts = Ks + NBH;
  u16t* attb = Vts + NBH;  // [B, T, H*D] internal bf16

  qkv_kernel<<<BH * NQT, 256, 0, stream>>>(x, y, Wq, Wk, Wv, Qs, Ks, Vts);
  attn_kernel<<<BH * NQT, 256, 0, stream>>>(Qs, Ks, Vts, attb);
  proj_kernel<<<(Bb * Tt) / 64, 256, 0, stream>>>(attb, Wp, bp, out);
}